// Round 4
// baseline (530.518 us; speedup 1.0000x reference)
//
#include <hip/hip_runtime.h>
#include <hip/hip_bf16.h>

// 3D shifted-window attention (Swin), D=H=W=32, WS=8, SS=4, NH=12, HD=32, N=512.
// Pass 0: bias precompute (bf16, pre-scaled by log2e, in S^T fragment order).
// Pass 1: repack qkv fp32 [vox][3,hd,nh] -> bf16 g_pack[part][nh][w][m][hd].
// Pass 2: attention (512 thr/block, one block per (window,head)); K XOR-swizzled
//         + V^T in LDS; S^T = mfma(K,Q); softmax w/o max-subtraction; shift-mask
//         as zeroing; PV via shared k-slot permutation. Output -> packed
//         g_opack[nh][w][hd][m] in full exclusive 64B lines (no write scatter).
// Pass 3: unpack g_opack -> out[vox][hd*12+nh] via LDS transpose, all coalesced.

typedef __attribute__((ext_vector_type(8))) short short8_t;   // 8 x bf16
typedef __attribute__((ext_vector_type(4))) float f32x4;

__device__ uint2 g_biasF[12 * 32 * 32 * 64];                  // 6.3 MB
__device__ uint4 g_pack4[3ULL * 12 * 64 * 512 * 32 / 8];      // 75.5 MB bf16
__device__ float g_opack[12ULL * 64 * 32 * 512];              // 50.3 MB f32

__device__ __forceinline__ unsigned short f2bf(float f) {
  __hip_bfloat16 h = __float2bfloat16(f);   // RNE; pairs fuse to cvt_pk
  return *reinterpret_cast<unsigned short*>(&h);
}
__device__ __forceinline__ unsigned pkbf2(float lo, float hi) {
  return (unsigned)f2bf(lo) | ((unsigned)f2bf(hi) << 16);
}

// ---------------- bias precompute: g_biasF[((nh*32+qt)*32+t)*64 + lane] -------
__global__ void bias_prep_kernel(const float* __restrict__ table) {
  int flat = blockIdx.x * 256 + threadIdx.x;      // 786432 threads
  int l  = flat & 63;
  int t  = (flat >> 6) & 31;
  int qt = (flat >> 11) & 31;
  int nh = flat >> 16;
  int ln = l & 15, g = l >> 4;
  int n = qt * 16 + ln;
  int dn = n >> 6, hn = (n >> 3) & 7, wn = n & 7;
  unsigned short bf[4];
#pragma unroll
  for (int r = 0; r < 4; ++r) {
    int m = t * 16 + g * 4 + r;
    int dm = m >> 6, hm = (m >> 3) & 7, wm = m & 7;
    int idx = (dn - dm + 7) * 225 + (hn - hm + 7) * 15 + (wn - wm + 7);
    float v = table[idx * 12 + nh] * 1.4426950408889634f;
    bf[r] = f2bf(v);
  }
  g_biasF[flat] = make_uint2((unsigned)bf[0] | ((unsigned)bf[1] << 16),
                             (unsigned)bf[2] | ((unsigned)bf[3] << 16));
}

// ---------------- pass 1: repack ----------------
__global__ __launch_bounds__(256, 4) void repack_kernel(
    const float* __restrict__ qkv) {
  __shared__ unsigned short S[8 * 1154];
  const int bid = blockIdx.x;               // 64*8*8 = 4096
  const int mh = bid & 7;
  const int md = (bid >> 3) & 7;
  const int w = bid >> 6;
  const int dblk = w >> 4, hblk = (w >> 2) & 3, wblk = w & 3;
  const int dd = (dblk * 8 + 4 + md) & 31;
  const int hh = (hblk * 8 + 4 + mh) & 31;
  const int w0 = wblk * 8 + 4;
  const int tid = threadIdx.x;

#pragma unroll
  for (int rep = 0; rep < 9; ++rep) {
    int t = rep * 256 + tid;
    unsigned v = (unsigned)t / 288u;
    int c4 = t - (int)v * 288;
    int ww = (w0 + (int)v) & 31;
    const float4 f = *(const float4*)(qkv + (((dd * 32 + hh) * 32 + ww) * 1152) + c4 * 4);
    *(uint2*)&S[v * 1154 + c4 * 4] = make_uint2(pkbf2(f.x, f.y), pkbf2(f.z, f.w));
  }
  __syncthreads();

  const int mbase = md * 64 + mh * 8;
  unsigned short* gp = (unsigned short*)g_pack4;
#pragma unroll
  for (int rep = 0; rep < 5; ++rep) {
    int t = rep * 256 + tid;                 // 1152 tasks
    if (t < 1152) {
      int chunk = t & 3;
      int mw = (t >> 2) & 7;
      int r = t >> 5;                        // 0..35
      int nh = r % 12;
      int part = r / 12;
      int ebase = mw * 1154 + part * 384 + chunk * 96 + nh;
      unsigned pk[4];
#pragma unroll
      for (int jj = 0; jj < 4; ++jj) {
        unsigned lo = S[ebase + (2 * jj) * 12];
        unsigned hi = S[ebase + (2 * jj + 1) * 12];
        pk[jj] = lo | (hi << 16);
      }
      size_t dst = ((((size_t)(part * 12 + nh) * 64 + w) * 512 + mbase + mw) * 32 + chunk * 8);
      *(uint4*)&gp[dst] = make_uint4(pk[0], pk[1], pk[2], pk[3]);
    }
  }
}

// ---------------- pass 2: attention (512 threads) ----------------
__global__ __launch_bounds__(512, 4) void swin_attn_kernel() {
  __shared__ __align__(16) unsigned short Klds[512 * 32];   // 32 KB, XOR-swz
  __shared__ __align__(16) unsigned short Vt[32 * 516];     // 33 KB

  const int bid = blockIdx.x;
  const int xcd = bid & 7;
  const int s = bid >> 3;
  const int quad = s >> 5;
  const int rem = s & 31;
  const int nh = quad * 4 + (rem & 3);
  const int w = xcd * 8 + (rem >> 2);
  const int dblk = w >> 4, hblk = (w >> 2) & 3, wblk = w & 3;
  const int bm = ((dblk == 3) ? 256 : 0) | ((hblk == 3) ? 32 : 0) |
                 ((wblk == 3) ? 4 : 0);

  const int tid = threadIdx.x;

  const unsigned short* gp = (const unsigned short*)g_pack4;
  const size_t base = ((size_t)nh * 64 + w) * (512 * 32);
  const unsigned short* Qg = gp + base;                           // part 0
  const unsigned short* Kg = gp + (size_t)1 * 12 * 64 * 512 * 32 + base;
  const unsigned short* Vg = gp + (size_t)2 * 12 * 64 * 512 * 32 + base;

  // ---- stage K: coalesced uint4 loads, swizzled b128 LDS writes ----
#pragma unroll
  for (int it = 0; it < 4; ++it) {
    int flat = it * 512 + tid;               // 0..2047
    int m = flat >> 2, chunk = flat & 3;
    uint4 d = *(const uint4*)(Kg + flat * 8);
    char* dst = (char*)Klds + m * 64 + ((chunk * 16) ^ ((m & 3) << 4));
    *(uint4*)dst = d;
  }
  // ---- stage V: coalesced uint4 loads, transpose to Vt[hd][m] ----
#pragma unroll
  for (int it = 0; it < 4; ++it) {
    int flat = it * 512 + tid;
    int m = flat >> 2, hc = flat & 3;
    uint4 d = *(const uint4*)(Vg + flat * 8);
    const unsigned u[4] = {d.x, d.y, d.z, d.w};
#pragma unroll
    for (int j = 0; j < 8; ++j) {
      unsigned val = (u[j >> 1] >> (16 * (j & 1))) & 0xffffu;
      Vt[(hc * 8 + j) * 516 + m] = (unsigned short)val;
    }
  }
  __syncthreads();

  const int l = tid & 63;
  const int wv = tid >> 6;                   // 0..7
  const int ln = l & 15;
  const int g = l >> 4;
  constexpr float SCL2E = 0.17677669529663687f * 1.4426950408889634f;

  float* gop = g_opack + ((size_t)nh * 64 + w) * (32 * 512);

#pragma unroll 1
  for (int it = 0; it < 4; ++it) {
    const int qt = wv * 4 + it;          // this wave's q-tile (16 rows)
    const int n = qt * 16 + ln;

    // Q B-fragment: one dwordx4 = hd 8g..8g+7 of token n
    const uint4 qd = *(const uint4*)(Qg + n * 32 + g * 8);
    union { unsigned u[4]; short8_t v; } qf;
    qf.u[0] = qd.x; qf.u[1] = qd.y; qf.u[2] = qd.z; qf.u[3] = qd.w;

    const int nAnd = n & bm;
    const uint2* bp = g_biasF + ((nh * 32 + qt) * 32) * 64 + l;
    float sum = 0.f;
    unsigned pb[64];    // P row-block, bf16-packed, in S^T fragment order

#pragma unroll
    for (int t = 0; t < 32; ++t) {
      const short8_t* kp = (const short8_t*)((const char*)Klds +
          ((t * 16 + ln) * 64 + ((g * 16) ^ ((ln & 3) << 4))));
      f32x4 acc =
          __builtin_amdgcn_mfma_f32_16x16x32_bf16(*kp, qf.v, (f32x4)(0.0f), 0, 0, 0);
      uint2 bw = bp[t * 64];
      const int mAnd = ((t << 4) | ((g & 1) << 2)) & bm;
      const bool keep = (nAnd == mAnd);
      float p0 = exp2f(fmaf(acc.x, SCL2E, __uint_as_float(bw.x << 16)));
      float p1 = exp2f(fmaf(acc.y, SCL2E, __uint_as_float(bw.x & 0xffff0000u)));
      float p2 = exp2f(fmaf(acc.z, SCL2E, __uint_as_float(bw.y << 16)));
      float p3 = exp2f(fmaf(acc.w, SCL2E, __uint_as_float(bw.y & 0xffff0000u)));
      p0 = keep ? p0 : 0.f;
      p1 = keep ? p1 : 0.f;
      p2 = keep ? p2 : 0.f;
      p3 = keep ? p3 : 0.f;
      sum += (p0 + p1) + (p2 + p3);
      pb[2 * t]     = pkbf2(p0, p1);
      pb[2 * t + 1] = pkbf2(p2, p3);
    }

    sum += __shfl_xor(sum, 16, 64);
    sum += __shfl_xor(sum, 32, 64);
    const float rinv = 1.0f / sum;

    // PV: O^T = V^T x P^T with shared k-slot permutation
    f32x4 o0 = (f32x4)(0.0f), o1 = (f32x4)(0.0f);
#pragma unroll
    for (int c = 0; c < 16; ++c) {
      union { unsigned u[4]; short8_t v; } pf;
      pf.u[0] = pb[4 * c + 0];
      pf.u[1] = pb[4 * c + 1];
      pf.u[2] = pb[4 * c + 2];
      pf.u[3] = pb[4 * c + 3];
      const int col = c * 32 + g * 4;
      union { unsigned u[4]; short8_t v; } a0, a1;
      const unsigned* v00 = (const unsigned*)&Vt[ln * 516 + col];
      const unsigned* v01 = (const unsigned*)&Vt[ln * 516 + col + 16];
      a0.u[0] = v00[0]; a0.u[1] = v00[1]; a0.u[2] = v01[0]; a0.u[3] = v01[1];
      const unsigned* v10 = (const unsigned*)&Vt[(16 + ln) * 516 + col];
      const unsigned* v11 = (const unsigned*)&Vt[(16 + ln) * 516 + col + 16];
      a1.u[0] = v10[0]; a1.u[1] = v10[1]; a1.u[2] = v11[0]; a1.u[3] = v11[1];
      o0 = __builtin_amdgcn_mfma_f32_16x16x32_bf16(a0.v, pf.v, o0, 0, 0, 0);
      o1 = __builtin_amdgcn_mfma_f32_16x16x32_bf16(a1.v, pf.v, o1, 0, 0, 0);
    }

    // packed store: row hd = g*4+r (+16), col n -> full exclusive 64B lines
#pragma unroll
    for (int r = 0; r < 4; ++r) {
      gop[(g * 4 + r) * 512 + n] = o0[r] * rinv;
      gop[(g * 4 + r + 16) * 512 + n] = o1[r] * rinv;
    }
  }
}

// ---------------- pass 3: unpack g_opack -> out ----------------
__global__ __launch_bounds__(256) void unpack_kernel(float* __restrict__ out) {
  __shared__ float S[32 * 388];             // 48.5 KB, stride 388 (16B-aligned rows)
  const int bid = blockIdx.x;               // 64*16 = 1024
  const int mc = bid & 15;
  const int w = bid >> 4;
  const int dblk = w >> 4, hblk = (w >> 2) & 3, wblk = w & 3;
  const int d0 = dblk * 8 + 4, h0 = hblk * 8 + 4, w0 = wblk * 8 + 4;
  const int tid = threadIdx.x;

  // load: (nh, hd, tk) -> S[m][hd*12+nh]
#pragma unroll
  for (int rep = 0; rep < 12; ++rep) {
    int task = rep * 256 + tid;             // 0..3071
    int tk = task & 7;
    int hd = (task >> 3) & 31;
    int nh = task >> 8;                     // 0..11
    const float4 f = *(const float4*)(g_opack +
        (((size_t)nh * 64 + w) * 32 + hd) * 512 + mc * 32 + tk * 4);
    float ff[4] = {f.x, f.y, f.z, f.w};
#pragma unroll
    for (int j = 0; j < 4; ++j) {
      S[(tk * 4 + j) * 388 + hd * 12 + nh] = ff[j];
    }
  }
  __syncthreads();

  // store: token-major, fully coalesced full-line writes
#pragma unroll
  for (int rep = 0; rep < 12; ++rep) {
    int task = rep * 256 + tid;             // 0..3071
    unsigned c4 = (unsigned)task % 96u;
    int ml = (int)((unsigned)task / 96u);
    int n = mc * 32 + ml;
    int dd = (d0 + (n >> 6)) & 31;
    int hh = (h0 + ((n >> 3) & 7)) & 31;
    int ww = (w0 + (n & 7)) & 31;
    const float4* src = (const float4*)&S[ml * 388 + c4 * 4];
    *(float4*)(out + ((size_t)((dd * 32 + hh) * 32 + ww)) * 384 + c4 * 4) = *src;
  }
}

extern "C" void kernel_launch(void* const* d_in, const int* in_sizes, int n_in,
                              void* d_out, int out_size, void* d_ws, size_t ws_size,
                              hipStream_t stream) {
  (void)in_sizes; (void)n_in; (void)out_size; (void)d_ws; (void)ws_size;
  const float* qkv = (const float*)d_in[0];          // [1,32,32,32,1152] fp32
  const float* bias_table = (const float*)d_in[1];   // [3375,12] fp32
  float* out = (float*)d_out;                        // [1,32,32,32,384] fp32

  bias_prep_kernel<<<3072, 256, 0, stream>>>(bias_table);
  repack_kernel<<<4096, 256, 0, stream>>>(qkv);
  swin_attn_kernel<<<768, 512, 0, stream>>>();
  unpack_kernel<<<1024, 256, 0, stream>>>(out);
}

// Round 5
// 361.440 us; speedup vs baseline: 1.4678x; 1.4678x over previous
//
#include <hip/hip_runtime.h>
#include <hip/hip_bf16.h>

// 3D shifted-window attention (Swin), D=H=W=32, WS=8, SS=4, NH=12, HD=32, N=512.
// Pass 0: bias precompute (bf16, pre-scaled by log2e, uint4 per (qt, c, lane)).
// Pass 1: repack qkv fp32 [vox][3,hd,nh] -> bf16 g_pack[part][nh][w][m][hd].
// Pass 2: attention, one block per (window,head), 256 thr. Only V^T in LDS
//         (33 KB -> 4 blocks/CU, 16 waves/CU). K and bias read straight from
//         packed global (coalesced, L2-resident via head-clustered XCD map).
//         QK and PV FUSED per t-pair c: S^T = mfma(K,Q) x2 -> exp -> pack pf ->
//         o += mfma(Vt, pf). No pb[64] array -> no spill, deep load pipelining.
// Pass 3: unpack g_opack -> out[vox][hd*12+nh] via LDS transpose, coalesced.

typedef __attribute__((ext_vector_type(8))) short short8_t;   // 8 x bf16
typedef __attribute__((ext_vector_type(4))) float f32x4;

__device__ uint4 g_biasF[12 * 32 * 16 * 64];                  // 6.3 MB
__device__ uint4 g_pack4[3ULL * 12 * 64 * 512 * 32 / 8];      // 75.5 MB bf16
__device__ float g_opack[12ULL * 64 * 32 * 512];              // 50.3 MB f32

__device__ __forceinline__ unsigned short f2bf(float f) {
  __hip_bfloat16 h = __float2bfloat16(f);   // RNE; pairs fuse to cvt_pk
  return *reinterpret_cast<unsigned short*>(&h);
}
__device__ __forceinline__ unsigned pkbf2(float lo, float hi) {
  return (unsigned)f2bf(lo) | ((unsigned)f2bf(hi) << 16);
}

// -------- bias precompute: g_biasF[((nh*32+qt)*16+c)*64 + lane] = 8 bf16 ------
// covering t-pair (2c, 2c+1): m = t*16 + (lane>>4)*4 + r, n = qt*16 + (lane&15)
__global__ void bias_prep_kernel(const float* __restrict__ table) {
  int flat = blockIdx.x * 256 + threadIdx.x;      // 393216 threads
  int l  = flat & 63;
  int c  = (flat >> 6) & 15;
  int qt = (flat >> 10) & 31;
  int nh = flat >> 15;
  int ln = l & 15, g = l >> 4;
  int n = qt * 16 + ln;
  int dn = n >> 6, hn = (n >> 3) & 7, wn = n & 7;
  unsigned short bf[8];
#pragma unroll
  for (int e = 0; e < 8; ++e) {
    int m = (2 * c + (e >> 2)) * 16 + g * 4 + (e & 3);
    int dm = m >> 6, hm = (m >> 3) & 7, wm = m & 7;
    int idx = (dn - dm + 7) * 225 + (hn - hm + 7) * 15 + (wn - wm + 7);
    float v = table[idx * 12 + nh] * 1.4426950408889634f;
    bf[e] = f2bf(v);
  }
  g_biasF[flat] = make_uint4(
      (unsigned)bf[0] | ((unsigned)bf[1] << 16),
      (unsigned)bf[2] | ((unsigned)bf[3] << 16),
      (unsigned)bf[4] | ((unsigned)bf[5] << 16),
      (unsigned)bf[6] | ((unsigned)bf[7] << 16));
}

// ---------------- pass 1: repack ----------------
__global__ __launch_bounds__(256, 4) void repack_kernel(
    const float* __restrict__ qkv) {
  __shared__ unsigned short S[8 * 1154];
  const int bid = blockIdx.x;               // 64*8*8 = 4096
  const int mh = bid & 7;
  const int md = (bid >> 3) & 7;
  const int w = bid >> 6;
  const int dblk = w >> 4, hblk = (w >> 2) & 3, wblk = w & 3;
  const int dd = (dblk * 8 + 4 + md) & 31;
  const int hh = (hblk * 8 + 4 + mh) & 31;
  const int w0 = wblk * 8 + 4;
  const int tid = threadIdx.x;

#pragma unroll
  for (int rep = 0; rep < 9; ++rep) {
    int t = rep * 256 + tid;
    unsigned v = (unsigned)t / 288u;
    int c4 = t - (int)v * 288;
    int ww = (w0 + (int)v) & 31;
    const float4 f = *(const float4*)(qkv + (((dd * 32 + hh) * 32 + ww) * 1152) + c4 * 4);
    *(uint2*)&S[v * 1154 + c4 * 4] = make_uint2(pkbf2(f.x, f.y), pkbf2(f.z, f.w));
  }
  __syncthreads();

  const int mbase = md * 64 + mh * 8;
  unsigned short* gp = (unsigned short*)g_pack4;
#pragma unroll
  for (int rep = 0; rep < 5; ++rep) {
    int t = rep * 256 + tid;                 // 1152 tasks
    if (t < 1152) {
      int chunk = t & 3;
      int mw = (t >> 2) & 7;
      int r = t >> 5;                        // 0..35
      int nh = r % 12;
      int part = r / 12;
      int ebase = mw * 1154 + part * 384 + chunk * 96 + nh;
      unsigned pk[4];
#pragma unroll
      for (int jj = 0; jj < 4; ++jj) {
        unsigned lo = S[ebase + (2 * jj) * 12];
        unsigned hi = S[ebase + (2 * jj + 1) * 12];
        pk[jj] = lo | (hi << 16);
      }
      size_t dst = ((((size_t)(part * 12 + nh) * 64 + w) * 512 + mbase + mw) * 32 + chunk * 8);
      *(uint4*)&gp[dst] = make_uint4(pk[0], pk[1], pk[2], pk[3]);
    }
  }
}

// ---------------- pass 2: attention (256 threads, fused QK+PV) ----------------
__global__ __launch_bounds__(256, 4) void swin_attn_kernel() {
  __shared__ __align__(16) unsigned short Vt[32 * 516];     // 33 KB only

  const int bid = blockIdx.x;
  // Head-clustered XCD map: XCD x (= bid&7) owns head x (64 windows) plus half
  // of head 8 + x/2 -> per-XCD L2 set: K 3 MB + bias 1 MB (resident).
  const int xcd = bid & 7;
  const int j = bid >> 3;                    // 0..95
  int nh, w;
  if (j < 64) { nh = xcd; w = j; }
  else        { nh = 8 + (xcd >> 1); w = (xcd & 1) * 32 + (j - 64); }
  const int dblk = w >> 4, hblk = (w >> 2) & 3, wblk = w & 3;
  const int bm = ((dblk == 3) ? 256 : 0) | ((hblk == 3) ? 32 : 0) |
                 ((wblk == 3) ? 4 : 0);

  const int tid = threadIdx.x;

  const unsigned short* gp = (const unsigned short*)g_pack4;
  const size_t base = ((size_t)nh * 64 + w) * (512 * 32);
  const unsigned short* Qg = gp + base;                           // part 0
  const unsigned short* Kg = gp + (size_t)1 * 12 * 64 * 512 * 32 + base;
  const unsigned short* Vg = gp + (size_t)2 * 12 * 64 * 512 * 32 + base;

  // ---- stage V: coalesced uint4 loads, transpose to Vt[hd][m] ----
#pragma unroll
  for (int it = 0; it < 8; ++it) {
    int flat = it * 256 + tid;               // 0..2047
    int m = flat >> 2, hc = flat & 3;
    uint4 d = *(const uint4*)(Vg + flat * 8);
    const unsigned u[4] = {d.x, d.y, d.z, d.w};
#pragma unroll
    for (int jj = 0; jj < 8; ++jj) {
      unsigned val = (u[jj >> 1] >> (16 * (jj & 1))) & 0xffffu;
      Vt[(hc * 8 + jj) * 516 + m] = (unsigned short)val;
    }
  }
  __syncthreads();

  const int l = tid & 63;
  const int wv = tid >> 6;                   // 0..3
  const int ln = l & 15;
  const int g = l >> 4;
  constexpr float SCL2E = 0.17677669529663687f * 1.4426950408889634f;

  float* gop = g_opack + ((size_t)nh * 64 + w) * (32 * 512);

#pragma unroll 1
  for (int it = 0; it < 8; ++it) {
    const int qt = wv * 8 + it;          // this wave's q-tile (16 rows)
    const int n = qt * 16 + ln;

    // Q B-fragment: one dwordx4 = hd 8g..8g+7 of token n
    const uint4 qd = *(const uint4*)(Qg + n * 32 + g * 8);
    union { unsigned u[4]; short8_t v; } qf;
    qf.u[0] = qd.x; qf.u[1] = qd.y; qf.u[2] = qd.z; qf.u[3] = qd.w;

    const int nAnd = n & bm;
    const uint4* bp = g_biasF + ((nh * 32 + qt) * 16) * 64 + l;
    float sum = 0.f;
    f32x4 o0 = (f32x4)(0.0f), o1 = (f32x4)(0.0f);

#pragma unroll
    for (int c = 0; c < 16; ++c) {
      // K A-fragments for t = 2c, 2c+1: coalesced dwordx4 straight from L2
      const uint4 kd0 = *(const uint4*)(Kg + (2 * c) * 512 + ln * 32 + g * 8);
      const uint4 kd1 = *(const uint4*)(Kg + (2 * c + 1) * 512 + ln * 32 + g * 8);
      union { unsigned u[4]; short8_t v; } k0, k1;
      k0.u[0] = kd0.x; k0.u[1] = kd0.y; k0.u[2] = kd0.z; k0.u[3] = kd0.w;
      k1.u[0] = kd1.x; k1.u[1] = kd1.y; k1.u[2] = kd1.z; k1.u[3] = kd1.w;
      const uint4 bw = bp[c * 64];

      f32x4 acc0 = __builtin_amdgcn_mfma_f32_16x16x32_bf16(k0.v, qf.v, (f32x4)(0.0f), 0, 0, 0);
      f32x4 acc1 = __builtin_amdgcn_mfma_f32_16x16x32_bf16(k1.v, qf.v, (f32x4)(0.0f), 0, 0, 0);

      // mask: bm bits {4,32,256}; m-bit4 (=t&1) not in bm -> one keep per c
      const int mAnd = ((c << 5) | ((g & 1) << 2)) & bm;
      const bool keep = (nAnd == mAnd);
      float p0 = exp2f(fmaf(acc0.x, SCL2E, __uint_as_float(bw.x << 16)));
      float p1 = exp2f(fmaf(acc0.y, SCL2E, __uint_as_float(bw.x & 0xffff0000u)));
      float p2 = exp2f(fmaf(acc0.z, SCL2E, __uint_as_float(bw.y << 16)));
      float p3 = exp2f(fmaf(acc0.w, SCL2E, __uint_as_float(bw.y & 0xffff0000u)));
      float p4 = exp2f(fmaf(acc1.x, SCL2E, __uint_as_float(bw.z << 16)));
      float p5 = exp2f(fmaf(acc1.y, SCL2E, __uint_as_float(bw.z & 0xffff0000u)));
      float p6 = exp2f(fmaf(acc1.z, SCL2E, __uint_as_float(bw.w << 16)));
      float p7 = exp2f(fmaf(acc1.w, SCL2E, __uint_as_float(bw.w & 0xffff0000u)));
      p0 = keep ? p0 : 0.f;  p1 = keep ? p1 : 0.f;
      p2 = keep ? p2 : 0.f;  p3 = keep ? p3 : 0.f;
      p4 = keep ? p4 : 0.f;  p5 = keep ? p5 : 0.f;
      p6 = keep ? p6 : 0.f;  p7 = keep ? p7 : 0.f;
      sum += (p0 + p1) + (p2 + p3);
      sum += (p4 + p5) + (p6 + p7);

      union { unsigned u[4]; short8_t v; } pf;
      pf.u[0] = pkbf2(p0, p1);
      pf.u[1] = pkbf2(p2, p3);
      pf.u[2] = pkbf2(p4, p5);
      pf.u[3] = pkbf2(p6, p7);

      // V A-fragments (shared k-slot permutation with pf)
      const int col = c * 32 + g * 4;
      union { unsigned u[4]; short8_t v; } a0, a1;
      const unsigned* v00 = (const unsigned*)&Vt[ln * 516 + col];
      const unsigned* v01 = (const unsigned*)&Vt[ln * 516 + col + 16];
      a0.u[0] = v00[0]; a0.u[1] = v00[1]; a0.u[2] = v01[0]; a0.u[3] = v01[1];
      const unsigned* v10 = (const unsigned*)&Vt[(16 + ln) * 516 + col];
      const unsigned* v11 = (const unsigned*)&Vt[(16 + ln) * 516 + col + 16];
      a1.u[0] = v10[0]; a1.u[1] = v10[1]; a1.u[2] = v11[0]; a1.u[3] = v11[1];
      o0 = __builtin_amdgcn_mfma_f32_16x16x32_bf16(a0.v, pf.v, o0, 0, 0, 0);
      o1 = __builtin_amdgcn_mfma_f32_16x16x32_bf16(a1.v, pf.v, o1, 0, 0, 0);
    }

    sum += __shfl_xor(sum, 16, 64);
    sum += __shfl_xor(sum, 32, 64);
    const float rinv = 1.0f / sum;

    // packed store: row hd = g*4+r (+16), col n -> full exclusive 64B lines
#pragma unroll
    for (int r = 0; r < 4; ++r) {
      gop[(g * 4 + r) * 512 + n] = o0[r] * rinv;
      gop[(g * 4 + r + 16) * 512 + n] = o1[r] * rinv;
    }
  }
}

// ---------------- pass 3: unpack g_opack -> out ----------------
__global__ __launch_bounds__(256) void unpack_kernel(float* __restrict__ out) {
  __shared__ float S[32 * 388];             // 48.5 KB
  const int bid = blockIdx.x;               // 64*16 = 1024
  const int mc = bid & 15;
  const int w = bid >> 4;
  const int dblk = w >> 4, hblk = (w >> 2) & 3, wblk = w & 3;
  const int d0 = dblk * 8 + 4, h0 = hblk * 8 + 4, w0 = wblk * 8 + 4;
  const int tid = threadIdx.x;

  // load: (nh, hd, tk) -> S[m][hd*12+nh]
#pragma unroll
  for (int rep = 0; rep < 12; ++rep) {
    int task = rep * 256 + tid;             // 0..3071
    int tk = task & 7;
    int hd = (task >> 3) & 31;
    int nh = task >> 8;                     // 0..11
    const float4 f = *(const float4*)(g_opack +
        (((size_t)nh * 64 + w) * 32 + hd) * 512 + mc * 32 + tk * 4);
    float ff[4] = {f.x, f.y, f.z, f.w};
#pragma unroll
    for (int jj = 0; jj < 4; ++jj) {
      S[(tk * 4 + jj) * 388 + hd * 12 + nh] = ff[jj];
    }
  }
  __syncthreads();

  // store: token-major, fully coalesced full-line writes
#pragma unroll
  for (int rep = 0; rep < 12; ++rep) {
    int task = rep * 256 + tid;             // 0..3071
    unsigned c4 = (unsigned)task % 96u;
    int ml = (int)((unsigned)task / 96u);
    int n = mc * 32 + ml;
    int dd = (d0 + (n >> 6)) & 31;
    int hh = (h0 + ((n >> 3) & 7)) & 31;
    int ww = (w0 + (n & 7)) & 31;
    const float4* src = (const float4*)&S[ml * 388 + c4 * 4];
    *(float4*)(out + ((size_t)((dd * 32 + hh) * 32 + ww)) * 384 + c4 * 4) = *src;
  }
}

extern "C" void kernel_launch(void* const* d_in, const int* in_sizes, int n_in,
                              void* d_out, int out_size, void* d_ws, size_t ws_size,
                              hipStream_t stream) {
  (void)in_sizes; (void)n_in; (void)out_size; (void)d_ws; (void)ws_size;
  const float* qkv = (const float*)d_in[0];          // [1,32,32,32,1152] fp32
  const float* bias_table = (const float*)d_in[1];   // [3375,12] fp32
  float* out = (float*)d_out;                        // [1,32,32,32,384] fp32

  bias_prep_kernel<<<1536, 256, 0, stream>>>(bias_table);
  repack_kernel<<<4096, 256, 0, stream>>>(qkv);
  swin_attn_kernel<<<768, 256, 0, stream>>>();
  unpack_kernel<<<1024, 256, 0, stream>>>(out);
}

// Round 6
// 159.002 us; speedup vs baseline: 3.3365x; 2.2732x over previous
//
#include <hip/hip_runtime.h>
#include <hip/hip_bf16.h>

// 3D shifted-window attention (Swin), D=H=W=32, WS=8, SS=4, NH=12, HD=32, N=512.
// Pass 0: bias precompute (bf16, pre-scaled by log2e, uint4 per (qt, c, lane)).
// Pass 1: repack qkv fp32 [vox][3,hd,nh] -> bf16 g_pack[part][nh][w][m][hd].
// Pass 2: attention, one block per (window,head), 512 thr, 8 waves x 4 q-tiles.
//         K (XOR-swizzled) + V^T in LDS (66 KB -> 2 blocks/CU, 4 waves/SIMD).
//         c-loop loads K/V fragments ONCE and feeds 4 q-tiles (4x LDS reuse).
//         Fused QK+PV: S^T = mfma(K,Q) -> exp -> pack -> o += mfma(Vt, pf).
//         Output -> g_opack[nh][w][qt][hd][tk16]: each wave writes a full 2 KB
//         contiguous region (no partial-line evictions).
// Pass 3: unpack g_opack -> out[vox][hd*12+nh] via LDS transpose, coalesced.

typedef __attribute__((ext_vector_type(8))) short short8_t;   // 8 x bf16
typedef __attribute__((ext_vector_type(4))) float f32x4;

__device__ uint4 g_biasF[12 * 32 * 16 * 64];                  // 6.3 MB
__device__ uint4 g_pack4[3ULL * 12 * 64 * 512 * 32 / 8];      // 75.5 MB bf16
__device__ float g_opack[12ULL * 64 * 32 * 512];              // 50.3 MB f32

__device__ __forceinline__ unsigned short f2bf(float f) {
  __hip_bfloat16 h = __float2bfloat16(f);   // RNE; pairs fuse to cvt_pk
  return *reinterpret_cast<unsigned short*>(&h);
}
__device__ __forceinline__ unsigned pkbf2(float lo, float hi) {
  return (unsigned)f2bf(lo) | ((unsigned)f2bf(hi) << 16);
}

// -------- bias precompute: g_biasF[((nh*32+qt)*16+c)*64 + lane] = 8 bf16 ------
// covering t-pair (2c, 2c+1): m = t*16 + (lane>>4)*4 + r, n = qt*16 + (lane&15)
__global__ void bias_prep_kernel(const float* __restrict__ table) {
  int flat = blockIdx.x * 256 + threadIdx.x;      // 393216 threads
  int l  = flat & 63;
  int c  = (flat >> 6) & 15;
  int qt = (flat >> 10) & 31;
  int nh = flat >> 15;
  int ln = l & 15, g = l >> 4;
  int n = qt * 16 + ln;
  int dn = n >> 6, hn = (n >> 3) & 7, wn = n & 7;
  unsigned short bf[8];
#pragma unroll
  for (int e = 0; e < 8; ++e) {
    int m = (2 * c + (e >> 2)) * 16 + g * 4 + (e & 3);
    int dm = m >> 6, hm = (m >> 3) & 7, wm = m & 7;
    int idx = (dn - dm + 7) * 225 + (hn - hm + 7) * 15 + (wn - wm + 7);
    float v = table[idx * 12 + nh] * 1.4426950408889634f;
    bf[e] = f2bf(v);
  }
  g_biasF[flat] = make_uint4(
      (unsigned)bf[0] | ((unsigned)bf[1] << 16),
      (unsigned)bf[2] | ((unsigned)bf[3] << 16),
      (unsigned)bf[4] | ((unsigned)bf[5] << 16),
      (unsigned)bf[6] | ((unsigned)bf[7] << 16));
}

// ---------------- pass 1: repack ----------------
__global__ __launch_bounds__(256, 4) void repack_kernel(
    const float* __restrict__ qkv) {
  __shared__ unsigned short S[8 * 1154];
  const int bid = blockIdx.x;               // 64*8*8 = 4096
  const int mh = bid & 7;
  const int md = (bid >> 3) & 7;
  const int w = bid >> 6;
  const int dblk = w >> 4, hblk = (w >> 2) & 3, wblk = w & 3;
  const int dd = (dblk * 8 + 4 + md) & 31;
  const int hh = (hblk * 8 + 4 + mh) & 31;
  const int w0 = wblk * 8 + 4;
  const int tid = threadIdx.x;

#pragma unroll
  for (int rep = 0; rep < 9; ++rep) {
    int t = rep * 256 + tid;
    unsigned v = (unsigned)t / 288u;
    int c4 = t - (int)v * 288;
    int ww = (w0 + (int)v) & 31;
    const float4 f = *(const float4*)(qkv + (((dd * 32 + hh) * 32 + ww) * 1152) + c4 * 4);
    *(uint2*)&S[v * 1154 + c4 * 4] = make_uint2(pkbf2(f.x, f.y), pkbf2(f.z, f.w));
  }
  __syncthreads();

  const int mbase = md * 64 + mh * 8;
  unsigned short* gp = (unsigned short*)g_pack4;
#pragma unroll
  for (int rep = 0; rep < 5; ++rep) {
    int t = rep * 256 + tid;                 // 1152 tasks
    if (t < 1152) {
      int chunk = t & 3;
      int mw = (t >> 2) & 7;
      int r = t >> 5;                        // 0..35
      int nh = r % 12;
      int part = r / 12;
      int ebase = mw * 1154 + part * 384 + chunk * 96 + nh;
      unsigned pk[4];
#pragma unroll
      for (int jj = 0; jj < 4; ++jj) {
        unsigned lo = S[ebase + (2 * jj) * 12];
        unsigned hi = S[ebase + (2 * jj + 1) * 12];
        pk[jj] = lo | (hi << 16);
      }
      size_t dst = ((((size_t)(part * 12 + nh) * 64 + w) * 512 + mbase + mw) * 32 + chunk * 8);
      *(uint4*)&gp[dst] = make_uint4(pk[0], pk[1], pk[2], pk[3]);
    }
  }
}

// -------- pass 2: attention (512 threads, 8 waves x 4 q-tiles, fused) --------
__global__ __launch_bounds__(512, 4) void swin_attn_kernel() {
  __shared__ __align__(16) unsigned short Klds[512 * 32];   // 32 KB, XOR-swz
  __shared__ __align__(16) unsigned short Vt[32 * 516];     // 33 KB

  const int bid = blockIdx.x;
  // Head-clustered XCD map: XCD x owns head x (64 windows) + half of head 8+x/2
  const int xcd = bid & 7;
  const int jb = bid >> 3;                   // 0..95
  int nh, w;
  if (jb < 64) { nh = xcd; w = jb; }
  else         { nh = 8 + (xcd >> 1); w = (xcd & 1) * 32 + (jb - 64); }
  const int dblk = w >> 4, hblk = (w >> 2) & 3, wblk = w & 3;
  const int bm = ((dblk == 3) ? 256 : 0) | ((hblk == 3) ? 32 : 0) |
                 ((wblk == 3) ? 4 : 0);

  const int tid = threadIdx.x;

  const unsigned short* gp = (const unsigned short*)g_pack4;
  const size_t base = ((size_t)nh * 64 + w) * (512 * 32);
  const unsigned short* Qg = gp + base;                           // part 0
  const unsigned short* Kg = gp + (size_t)1 * 12 * 64 * 512 * 32 + base;
  const unsigned short* Vg = gp + (size_t)2 * 12 * 64 * 512 * 32 + base;

  // ---- stage K: coalesced uint4 loads, swizzled b128 LDS writes ----
#pragma unroll
  for (int itr = 0; itr < 4; ++itr) {
    int flat = itr * 512 + tid;              // 0..2047
    int m = flat >> 2, chunk = flat & 3;
    uint4 d = *(const uint4*)(Kg + flat * 8);
    char* dst = (char*)Klds + m * 64 + ((chunk * 16) ^ ((m & 3) << 4));
    *(uint4*)dst = d;
  }
  // ---- stage V: coalesced uint4 loads, transpose to Vt[hd][m] ----
#pragma unroll
  for (int itr = 0; itr < 4; ++itr) {
    int flat = itr * 512 + tid;
    int m = flat >> 2, hc = flat & 3;
    uint4 d = *(const uint4*)(Vg + flat * 8);
    const unsigned u[4] = {d.x, d.y, d.z, d.w};
#pragma unroll
    for (int jj = 0; jj < 8; ++jj) {
      Vt[(hc * 8 + jj) * 516 + m] =
          (unsigned short)((u[jj >> 1] >> (16 * (jj & 1))) & 0xffffu);
    }
  }
  __syncthreads();

  const int l = tid & 63;
  const int wv = tid >> 6;                   // 0..7, owns q-tiles wv*4..wv*4+3
  const int ln = l & 15;
  const int g = l >> 4;
  constexpr float SCL2E = 0.17677669529663687f * 1.4426950408889634f;

  union frag { unsigned u[4]; short8_t v; };

  // Q fragments for the wave's 4 q-tiles
  frag qf[4];
#pragma unroll
  for (int it = 0; it < 4; ++it) {
    const int n = (wv * 4 + it) * 16 + ln;
    const uint4 qd = *(const uint4*)(Qg + n * 32 + g * 8);
    qf[it].u[0] = qd.x; qf[it].u[1] = qd.y; qf[it].u[2] = qd.z; qf[it].u[3] = qd.w;
  }
  f32x4 o0[4], o1[4];
  float sum[4];
#pragma unroll
  for (int it = 0; it < 4; ++it) {
    o0[it] = (f32x4)(0.0f); o1[it] = (f32x4)(0.0f); sum[it] = 0.f;
  }

  const uint4* bp = g_biasF + ((nh * 32 + wv * 4) * 16) * 64 + l;

#define CLOOP(MASKED)                                                          \
  _Pragma("unroll 1")                                                          \
  for (int c = 0; c < 16; ++c) {                                               \
    frag k0, k1, a0, a1;                                                       \
    k0.v = *(const short8_t*)((const char*)Klds +                              \
        (((2 * c) * 16 + ln) * 64 + ((g * 16) ^ ((ln & 3) << 4))));            \
    k1.v = *(const short8_t*)((const char*)Klds +                              \
        (((2 * c + 1) * 16 + ln) * 64 + ((g * 16) ^ ((ln & 3) << 4))));        \
    {                                                                          \
      const int col = c * 32 + g * 4;                                          \
      const unsigned* v00 = (const unsigned*)&Vt[ln * 516 + col];              \
      const unsigned* v01 = (const unsigned*)&Vt[ln * 516 + col + 16];         \
      a0.u[0] = v00[0]; a0.u[1] = v00[1]; a0.u[2] = v01[0]; a0.u[3] = v01[1];  \
      const unsigned* v10 = (const unsigned*)&Vt[(16 + ln) * 516 + col];       \
      const unsigned* v11 = (const unsigned*)&Vt[(16 + ln) * 516 + col + 16];  \
      a1.u[0] = v10[0]; a1.u[1] = v10[1]; a1.u[2] = v11[0]; a1.u[3] = v11[1];  \
    }                                                                          \
    _Pragma("unroll")                                                          \
    for (int it = 0; it < 4; ++it) {                                           \
      f32x4 acc0 = __builtin_amdgcn_mfma_f32_16x16x32_bf16(                    \
          k0.v, qf[it].v, (f32x4)(0.0f), 0, 0, 0);                             \
      f32x4 acc1 = __builtin_amdgcn_mfma_f32_16x16x32_bf16(                    \
          k1.v, qf[it].v, (f32x4)(0.0f), 0, 0, 0);                             \
      const uint4 bw = bp[(it * 16 + c) * 64];                                 \
      float p0 = exp2f(fmaf(acc0.x, SCL2E, __uint_as_float(bw.x << 16)));      \
      float p1 = exp2f(fmaf(acc0.y, SCL2E, __uint_as_float(bw.x & 0xffff0000u))); \
      float p2 = exp2f(fmaf(acc0.z, SCL2E, __uint_as_float(bw.y << 16)));      \
      float p3 = exp2f(fmaf(acc0.w, SCL2E, __uint_as_float(bw.y & 0xffff0000u))); \
      float p4 = exp2f(fmaf(acc1.x, SCL2E, __uint_as_float(bw.z << 16)));      \
      float p5 = exp2f(fmaf(acc1.y, SCL2E, __uint_as_float(bw.z & 0xffff0000u))); \
      float p6 = exp2f(fmaf(acc1.z, SCL2E, __uint_as_float(bw.w << 16)));      \
      float p7 = exp2f(fmaf(acc1.w, SCL2E, __uint_as_float(bw.w & 0xffff0000u))); \
      if (MASKED) {                                                            \
        const int nAnd = ((wv * 4 + it) * 16 + ln) & bm;                       \
        const int mAnd = ((c << 5) | ((g & 1) << 2)) & bm;                     \
        const bool keep = (nAnd == mAnd);                                      \
        p0 = keep ? p0 : 0.f;  p1 = keep ? p1 : 0.f;                           \
        p2 = keep ? p2 : 0.f;  p3 = keep ? p3 : 0.f;                           \
        p4 = keep ? p4 : 0.f;  p5 = keep ? p5 : 0.f;                           \
        p6 = keep ? p6 : 0.f;  p7 = keep ? p7 : 0.f;                           \
      }                                                                        \
      sum[it] += ((p0 + p1) + (p2 + p3)) + ((p4 + p5) + (p6 + p7));            \
      frag pf;                                                                 \
      pf.u[0] = pkbf2(p0, p1);  pf.u[1] = pkbf2(p2, p3);                       \
      pf.u[2] = pkbf2(p4, p5);  pf.u[3] = pkbf2(p6, p7);                       \
      o0[it] = __builtin_amdgcn_mfma_f32_16x16x32_bf16(a0.v, pf.v, o0[it], 0, 0, 0); \
      o1[it] = __builtin_amdgcn_mfma_f32_16x16x32_bf16(a1.v, pf.v, o1[it], 0, 0, 0); \
    }                                                                          \
  }

  if (bm == 0) { CLOOP(false) } else { CLOOP(true) }
#undef CLOOP

  // ---- epilogue: per q-tile row-sum reduce + packed contiguous store ----
#pragma unroll
  for (int it = 0; it < 4; ++it) {
    float s = sum[it];
    s += __shfl_xor(s, 16, 64);
    s += __shfl_xor(s, 32, 64);
    const float rinv = 1.0f / s;
    const int qt = wv * 4 + it;
    float* gop = g_opack + ((size_t)nh * 64 + w) * 16384 + qt * 512 + ln;
#pragma unroll
    for (int r = 0; r < 4; ++r) {
      gop[(g * 4 + r) * 16] = o0[it][r] * rinv;
      gop[(g * 4 + r + 16) * 16] = o1[it][r] * rinv;
    }
  }
}

// ---------------- pass 3: unpack g_opack -> out ----------------
__global__ __launch_bounds__(256) void unpack_kernel(float* __restrict__ out) {
  __shared__ float S[32 * 388];             // 48.5 KB
  const int bid = blockIdx.x;               // 64*16 = 1024
  const int mc = bid & 15;
  const int w = bid >> 4;
  const int dblk = w >> 4, hblk = (w >> 2) & 3, wblk = w & 3;
  const int d0 = dblk * 8 + 4, h0 = hblk * 8 + 4, w0 = wblk * 8 + 4;
  const int tid = threadIdx.x;

  // load: gop[nh][w][qt][hd][tk16] -> S[ml][hd*12+nh]
#pragma unroll
  for (int rep = 0; rep < 12; ++rep) {
    int task = rep * 256 + tid;             // 0..3071
    int tk4 = task & 3;
    int q2 = (task >> 2) & 1;
    int hd = (task >> 3) & 31;
    int nh = task >> 8;                     // 0..11
    const float4 f = *(const float4*)(g_opack +
        ((size_t)nh * 64 + w) * 16384 + (size_t)(mc * 2 + q2) * 512 + hd * 16 + tk4 * 4);
    float ff[4] = {f.x, f.y, f.z, f.w};
#pragma unroll
    for (int jj = 0; jj < 4; ++jj) {
      S[(q2 * 16 + tk4 * 4 + jj) * 388 + hd * 12 + nh] = ff[jj];
    }
  }
  __syncthreads();

  // store: token-major, fully coalesced full-line writes
#pragma unroll
  for (int rep = 0; rep < 12; ++rep) {
    int task = rep * 256 + tid;             // 0..3071
    unsigned c4 = (unsigned)task % 96u;
    int ml = (int)((unsigned)task / 96u);
    int n = mc * 32 + ml;
    int dd = (d0 + (n >> 6)) & 31;
    int hh = (h0 + ((n >> 3) & 7)) & 31;
    int ww = (w0 + (n & 7)) & 31;
    const float4* src = (const float4*)&S[ml * 388 + c4 * 4];
    *(float4*)(out + ((size_t)((dd * 32 + hh) * 32 + ww)) * 384 + c4 * 4) = *src;
  }
}

extern "C" void kernel_launch(void* const* d_in, const int* in_sizes, int n_in,
                              void* d_out, int out_size, void* d_ws, size_t ws_size,
                              hipStream_t stream) {
  (void)in_sizes; (void)n_in; (void)out_size; (void)d_ws; (void)ws_size;
  const float* qkv = (const float*)d_in[0];          // [1,32,32,32,1152] fp32
  const float* bias_table = (const float*)d_in[1];   // [3375,12] fp32
  float* out = (float*)d_out;                        // [1,32,32,32,384] fp32

  bias_prep_kernel<<<1536, 256, 0, stream>>>(bias_table);
  repack_kernel<<<4096, 256, 0, stream>>>(qkv);
  swin_attn_kernel<<<768, 512, 0, stream>>>();
  unpack_kernel<<<1024, 256, 0, stream>>>(out);
}

// Round 7
// 151.507 us; speedup vs baseline: 3.5016x; 1.0495x over previous
//
#include <hip/hip_runtime.h>
#include <hip/hip_bf16.h>

// 3D shifted-window attention (Swin), D=H=W=32, WS=8, SS=4, NH=12, HD=32, N=512.
// Pass 1 (prep): [blocks 0..4095] repack qkv fp32 -> bf16 g_pack[part][nh][w][m][hd]
//                with Q pre-scaled by scale*log2e;
//                [blocks 4096..5631] bias -> fp32 g_biasC (bias*log2e) in exact
//                S^T D-fragment order, fed to the QK MFMA as the C operand.
// Pass 2 (attn): one block per (window,head), 512 thr, 8 waves x 4 q-tiles.
//         K (XOR-swizzled) + V^T in LDS. Per c: load K/V frags once, feed 4
//         q-tiles. acc = mfma(K,Q,biasC); p = exp2(acc); pack pf;
//         row-sum via ones-MFMA (sumac = mfma(ones, pf, sumac), every lane gets
//         its full row sum -> no shuffles); mask via 4 cndmask on pf words.
//         o += mfma(Vt, pf). Output -> g_opack[nh][w][qt][hd][tk16] contiguous.
// Pass 3: unpack g_opack -> out[vox][hd*12+nh] via LDS transpose, coalesced.

typedef __attribute__((ext_vector_type(8))) short short8_t;   // 8 x bf16
typedef __attribute__((ext_vector_type(4))) float f32x4;

__device__ float g_biasC[12 * 32 * 16 * 64 * 8];              // 12.6 MB fp32
__device__ uint4 g_pack4[3ULL * 12 * 64 * 512 * 32 / 8];      // 75.5 MB bf16
__device__ float g_opack[12ULL * 64 * 32 * 512];              // 50.3 MB f32

constexpr float SCL2E = 0.17677669529663687f * 1.4426950408889634f; // scale*log2e
constexpr float LOG2E = 1.4426950408889634f;

__device__ __forceinline__ unsigned short f2bf(float f) {
  __hip_bfloat16 h = __float2bfloat16(f);   // RNE; pairs fuse to cvt_pk
  return *reinterpret_cast<unsigned short*>(&h);
}
__device__ __forceinline__ unsigned pkbf2(float lo, float hi) {
  return (unsigned)f2bf(lo) | ((unsigned)f2bf(hi) << 16);
}

// ---------------- pass 1: repack + bias prep (merged grid) ----------------
__global__ __launch_bounds__(256, 4) void prep_kernel(
    const float* __restrict__ qkv, const float* __restrict__ table) {
  __shared__ unsigned short S[8 * 1154];
  const int bid = blockIdx.x;
  const int tid = threadIdx.x;

  if (bid >= 4096) {
    // ---- bias part: g_biasC[flat*8 + e] = bias(n, m(e)) * log2e, fp32 ----
    int flat = (bid - 4096) * 256 + tid;    // 0..393215 = (nh, qt, c, lane)
    int l  = flat & 63;
    int c  = (flat >> 6) & 15;
    int qt = (flat >> 10) & 31;
    int nh = flat >> 15;
    int ln = l & 15, g = l >> 4;
    int n = qt * 16 + ln;
    int dn = n >> 6, hn = (n >> 3) & 7, wn = n & 7;
    float e[8];
#pragma unroll
    for (int r = 0; r < 8; ++r) {
      int m = 32 * c + (r >> 2) * 16 + g * 4 + (r & 3);
      int dm = m >> 6, hm = (m >> 3) & 7, wm = m & 7;
      int idx = (dn - dm + 7) * 225 + (hn - hm + 7) * 15 + (wn - wm + 7);
      e[r] = table[idx * 12 + nh] * LOG2E;
    }
    *(float4*)&g_biasC[flat * 8]     = make_float4(e[0], e[1], e[2], e[3]);
    *(float4*)&g_biasC[flat * 8 + 4] = make_float4(e[4], e[5], e[6], e[7]);
    return;
  }

  // ---- repack part ----
  const int mh = bid & 7;
  const int md = (bid >> 3) & 7;
  const int w = bid >> 6;
  const int dblk = w >> 4, hblk = (w >> 2) & 3, wblk = w & 3;
  const int dd = (dblk * 8 + 4 + md) & 31;
  const int hh = (hblk * 8 + 4 + mh) & 31;
  const int w0 = wblk * 8 + 4;

#pragma unroll
  for (int rep = 0; rep < 9; ++rep) {
    int t = rep * 256 + tid;
    unsigned v = (unsigned)t / 288u;
    int c4 = t - (int)v * 288;
    int ww = (w0 + (int)v) & 31;
    float4 f = *(const float4*)(qkv + (((dd * 32 + hh) * 32 + ww) * 1152) + c4 * 4);
    if (c4 < 96) {      // Q channels (0..383): pre-scale by scale*log2e
      f.x *= SCL2E; f.y *= SCL2E; f.z *= SCL2E; f.w *= SCL2E;
    }
    *(uint2*)&S[v * 1154 + c4 * 4] = make_uint2(pkbf2(f.x, f.y), pkbf2(f.z, f.w));
  }
  __syncthreads();

  const int mbase = md * 64 + mh * 8;
  unsigned short* gp = (unsigned short*)g_pack4;
#pragma unroll
  for (int rep = 0; rep < 5; ++rep) {
    int t = rep * 256 + tid;                 // 1152 tasks
    if (t < 1152) {
      int chunk = t & 3;
      int mw = (t >> 2) & 7;
      int r = t >> 5;                        // 0..35
      int nh = r % 12;
      int part = r / 12;
      int ebase = mw * 1154 + part * 384 + chunk * 96 + nh;
      unsigned pk[4];
#pragma unroll
      for (int jj = 0; jj < 4; ++jj) {
        unsigned lo = S[ebase + (2 * jj) * 12];
        unsigned hi = S[ebase + (2 * jj + 1) * 12];
        pk[jj] = lo | (hi << 16);
      }
      size_t dst = ((((size_t)(part * 12 + nh) * 64 + w) * 512 + mbase + mw) * 32 + chunk * 8);
      *(uint4*)&gp[dst] = make_uint4(pk[0], pk[1], pk[2], pk[3]);
    }
  }
}

// -------- pass 2: attention (512 threads, 8 waves x 4 q-tiles, fused) --------
__global__ __launch_bounds__(512, 4) void swin_attn_kernel() {
  __shared__ __align__(16) unsigned short Klds[512 * 32];   // 32 KB, XOR-swz
  __shared__ __align__(16) unsigned short Vt[32 * 516];     // 33 KB

  const int bid = blockIdx.x;
  // Head-clustered XCD map: XCD x owns head x (64 windows) + half of head 8+x/2
  const int xcd = bid & 7;
  const int jb = bid >> 3;                   // 0..95
  int nh, w;
  if (jb < 64) { nh = xcd; w = jb; }
  else         { nh = 8 + (xcd >> 1); w = (xcd & 1) * 32 + (jb - 64); }
  const int dblk = w >> 4, hblk = (w >> 2) & 3, wblk = w & 3;
  const int bm = ((dblk == 3) ? 256 : 0) | ((hblk == 3) ? 32 : 0) |
                 ((wblk == 3) ? 4 : 0);

  const int tid = threadIdx.x;

  const unsigned short* gp = (const unsigned short*)g_pack4;
  const size_t base = ((size_t)nh * 64 + w) * (512 * 32);
  const unsigned short* Qg = gp + base;                           // part 0
  const unsigned short* Kg = gp + (size_t)1 * 12 * 64 * 512 * 32 + base;
  const unsigned short* Vg = gp + (size_t)2 * 12 * 64 * 512 * 32 + base;

  // ---- stage K: coalesced uint4 loads, swizzled b128 LDS writes ----
#pragma unroll
  for (int itr = 0; itr < 4; ++itr) {
    int flat = itr * 512 + tid;              // 0..2047
    int m = flat >> 2, chunk = flat & 3;
    uint4 d = *(const uint4*)(Kg + flat * 8);
    char* dst = (char*)Klds + m * 64 + ((chunk * 16) ^ ((m & 3) << 4));
    *(uint4*)dst = d;
  }
  // ---- stage V: coalesced uint4 loads, transpose to Vt[hd][m] ----
#pragma unroll
  for (int itr = 0; itr < 4; ++itr) {
    int flat = itr * 512 + tid;
    int m = flat >> 2, hc = flat & 3;
    uint4 d = *(const uint4*)(Vg + flat * 8);
    const unsigned u[4] = {d.x, d.y, d.z, d.w};
#pragma unroll
    for (int jj = 0; jj < 8; ++jj) {
      Vt[(hc * 8 + jj) * 516 + m] =
          (unsigned short)((u[jj >> 1] >> (16 * (jj & 1))) & 0xffffu);
    }
  }
  __syncthreads();

  const int l = tid & 63;
  const int wv = tid >> 6;                   // 0..7, owns q-tiles wv*4..wv*4+3
  const int ln = l & 15;
  const int g = l >> 4;

  union frag { unsigned u[4]; short8_t v; };

  // Q fragments for the wave's 4 q-tiles (Q already pre-scaled)
  frag qf[4];
#pragma unroll
  for (int it = 0; it < 4; ++it) {
    const int n = (wv * 4 + it) * 16 + ln;
    const uint4 qd = *(const uint4*)(Qg + n * 32 + g * 8);
    qf[it].u[0] = qd.x; qf[it].u[1] = qd.y; qf[it].u[2] = qd.z; qf[it].u[3] = qd.w;
  }
  f32x4 o0[4], o1[4], sumac[4];
#pragma unroll
  for (int it = 0; it < 4; ++it) {
    o0[it] = (f32x4)(0.0f); o1[it] = (f32x4)(0.0f); sumac[it] = (f32x4)(0.0f);
  }
  frag ones;
  ones.u[0] = 0x3F803F80u; ones.u[1] = 0x3F803F80u;
  ones.u[2] = 0x3F803F80u; ones.u[3] = 0x3F803F80u;

  // bias fragment stream (fp32, D-fragment order)
  const f32x4* bp = (const f32x4*)g_biasC +
      ((size_t)(nh * 32 + wv * 4) * 16) * 128 + l * 2;

  int nA[4];
#pragma unroll
  for (int it = 0; it < 4; ++it) nA[it] = ((wv * 4 + it) * 16 + ln) & bm;

#define CLOOP(MASKED)                                                          \
  _Pragma("unroll 1")                                                          \
  for (int c = 0; c < 16; ++c) {                                               \
    frag k0, k1, a0, a1;                                                       \
    k0.v = *(const short8_t*)((const char*)Klds +                              \
        (((2 * c) * 16 + ln) * 64 + ((g * 16) ^ ((ln & 3) << 4))));            \
    k1.v = *(const short8_t*)((const char*)Klds +                              \
        (((2 * c + 1) * 16 + ln) * 64 + ((g * 16) ^ ((ln & 3) << 4))));        \
    {                                                                          \
      const int col = c * 32 + g * 4;                                          \
      const unsigned* v00 = (const unsigned*)&Vt[ln * 516 + col];              \
      const unsigned* v01 = (const unsigned*)&Vt[ln * 516 + col + 16];         \
      a0.u[0] = v00[0]; a0.u[1] = v00[1]; a0.u[2] = v01[0]; a0.u[3] = v01[1];  \
      const unsigned* v10 = (const unsigned*)&Vt[(16 + ln) * 516 + col];       \
      const unsigned* v11 = (const unsigned*)&Vt[(16 + ln) * 516 + col + 16];  \
      a1.u[0] = v10[0]; a1.u[1] = v10[1]; a1.u[2] = v11[0]; a1.u[3] = v11[1];  \
    }                                                                          \
    const int mAnd = ((c << 5) | ((g & 1) << 2)) & bm;                         \
    _Pragma("unroll")                                                          \
    for (int it = 0; it < 4; ++it) {                                           \
      const f32x4 bc0 = bp[(it * 16 + c) * 128];                               \
      const f32x4 bc1 = bp[(it * 16 + c) * 128 + 1];                           \
      f32x4 acc0 = __builtin_amdgcn_mfma_f32_16x16x32_bf16(                    \
          k0.v, qf[it].v, bc0, 0, 0, 0);                                       \
      f32x4 acc1 = __builtin_amdgcn_mfma_f32_16x16x32_bf16(                    \
          k1.v, qf[it].v, bc1, 0, 0, 0);                                       \
      float p0 = exp2f(acc0[0]);                                               \
      float p1 = exp2f(acc0[1]);                                               \
      float p2 = exp2f(acc0[2]);                                               \
      float p3 = exp2f(acc0[3]);                                               \
      float p4 = exp2f(acc1[0]);                                               \
      float p5 = exp2f(acc1[1]);                                               \
      float p6 = exp2f(acc1[2]);                                               \
      float p7 = exp2f(acc1[3]);                                               \
      frag pf;                                                                 \
      pf.u[0] = pkbf2(p0, p1);  pf.u[1] = pkbf2(p2, p3);                       \
      pf.u[2] = pkbf2(p4, p5);  pf.u[3] = pkbf2(p6, p7);                       \
      if (MASKED) {                                                            \
        const bool keep = (nA[it] == mAnd);                                    \
        pf.u[0] = keep ? pf.u[0] : 0u;                                         \
        pf.u[1] = keep ? pf.u[1] : 0u;                                         \
        pf.u[2] = keep ? pf.u[2] : 0u;                                         \
        pf.u[3] = keep ? pf.u[3] : 0u;                                         \
      }                                                                        \
      sumac[it] = __builtin_amdgcn_mfma_f32_16x16x32_bf16(                     \
          ones.v, pf.v, sumac[it], 0, 0, 0);                                   \
      o0[it] = __builtin_amdgcn_mfma_f32_16x16x32_bf16(a0.v, pf.v, o0[it], 0, 0, 0); \
      o1[it] = __builtin_amdgcn_mfma_f32_16x16x32_bf16(a1.v, pf.v, o1[it], 0, 0, 0); \
    }                                                                          \
  }

  if (bm == 0) { CLOOP(false) } else { CLOOP(true) }
#undef CLOOP

  // ---- epilogue: every lane's sumac[it][0] is its own full row-sum ----
#pragma unroll
  for (int it = 0; it < 4; ++it) {
    const float rinv = 1.0f / sumac[it][0];
    const int qt = wv * 4 + it;
    float* gop = g_opack + ((size_t)nh * 64 + w) * 16384 + qt * 512 + ln;
#pragma unroll
    for (int r = 0; r < 4; ++r) {
      gop[(g * 4 + r) * 16] = o0[it][r] * rinv;
      gop[(g * 4 + r + 16) * 16] = o1[it][r] * rinv;
    }
  }
}

// ---------------- pass 3: unpack g_opack -> out ----------------
__global__ __launch_bounds__(256) void unpack_kernel(float* __restrict__ out) {
  __shared__ float S[32 * 388];             // 48.5 KB
  const int bid = blockIdx.x;               // 64*16 = 1024
  const int mc = bid & 15;
  const int w = bid >> 4;
  const int dblk = w >> 4, hblk = (w >> 2) & 3, wblk = w & 3;
  const int d0 = dblk * 8 + 4, h0 = hblk * 8 + 4, w0 = wblk * 8 + 4;
  const int tid = threadIdx.x;

  // load: gop[nh][w][qt][hd][tk16] -> S[ml][hd*12+nh]
#pragma unroll
  for (int rep = 0; rep < 12; ++rep) {
    int task = rep * 256 + tid;             // 0..3071
    int tk4 = task & 3;
    int q2 = (task >> 2) & 1;
    int hd = (task >> 3) & 31;
    int nh = task >> 8;                     // 0..11
    const float4 f = *(const float4*)(g_opack +
        ((size_t)nh * 64 + w) * 16384 + (size_t)(mc * 2 + q2) * 512 + hd * 16 + tk4 * 4);
    float ff[4] = {f.x, f.y, f.z, f.w};
#pragma unroll
    for (int jj = 0; jj < 4; ++jj) {
      S[(q2 * 16 + tk4 * 4 + jj) * 388 + hd * 12 + nh] = ff[jj];
    }
  }
  __syncthreads();

  // store: token-major, fully coalesced full-line writes
#pragma unroll
  for (int rep = 0; rep < 12; ++rep) {
    int task = rep * 256 + tid;             // 0..3071
    unsigned c4 = (unsigned)task % 96u;
    int ml = (int)((unsigned)task / 96u);
    int n = mc * 32 + ml;
    int dd = (d0 + (n >> 6)) & 31;
    int hh = (h0 + ((n >> 3) & 7)) & 31;
    int ww = (w0 + (n & 7)) & 31;
    const float4* src = (const float4*)&S[ml * 388 + c4 * 4];
    *(float4*)(out + ((size_t)((dd * 32 + hh) * 32 + ww)) * 384 + c4 * 4) = *src;
  }
}

extern "C" void kernel_launch(void* const* d_in, const int* in_sizes, int n_in,
                              void* d_out, int out_size, void* d_ws, size_t ws_size,
                              hipStream_t stream) {
  (void)in_sizes; (void)n_in; (void)out_size; (void)d_ws; (void)ws_size;
  const float* qkv = (const float*)d_in[0];          // [1,32,32,32,1152] fp32
  const float* bias_table = (const float*)d_in[1];   // [3375,12] fp32
  float* out = (float*)d_out;                        // [1,32,32,32,384] fp32

  prep_kernel<<<5632, 256, 0, stream>>>(qkv, bias_table);
  swin_attn_kernel<<<768, 512, 0, stream>>>();
  unpack_kernel<<<1024, 256, 0, stream>>>(out);
}

// Round 8
// 119.197 us; speedup vs baseline: 4.4508x; 1.2711x over previous
//
#include <hip/hip_runtime.h>
#include <hip/hip_bf16.h>

// 3D shifted-window attention (Swin), D=H=W=32, WS=8, SS=4, NH=12, HD=32, N=512.
// Pass 1 (prep): [blocks 0..4095] repack qkv fp32 -> bf16 g_pack[part][nh][w][m][hd]
//                with Q pre-scaled by scale*log2e;
//                [blocks 4096..5631] bias -> fp32 g_biasC (bias*log2e) in exact
//                S^T D-fragment order, fed to the QK MFMA as the C operand.
// Pass 2 (attn): one block per (window,head), 512 thr, 8 waves x 4 q-tiles.
//         K (XOR-swizzled) + V^T in LDS. Per c: load K/V frags once, feed 4
//         q-tiles. acc = mfma(K,Q,biasC); p = v_exp_f32(acc) (raw builtin —
//         OCML exp2f was ~40% of all VALU issue); pack pf (cvt_pk);
//         row-sum via ones-MFMA; mask via 4 cndmask on pf words;
//         o += mfma(Vt, pf). Output -> g_opack (bf16) [nh][w][qt][hd][tk16].
// Pass 3: unpack g_opack (bf16) -> out[vox][hd*12+nh] fp32 via LDS transpose.

typedef __attribute__((ext_vector_type(8))) short short8_t;   // 8 x bf16
typedef __attribute__((ext_vector_type(4))) float f32x4;

__device__ float g_biasC[12 * 32 * 16 * 64 * 8];              // 12.6 MB fp32
__device__ uint4 g_pack4[3ULL * 12 * 64 * 512 * 32 / 8];      // 75.5 MB bf16
__device__ unsigned short g_opack[12ULL * 64 * 32 * 512];     // 25.2 MB bf16

constexpr float SCL2E = 0.17677669529663687f * 1.4426950408889634f; // scale*log2e
constexpr float LOG2E = 1.4426950408889634f;

__device__ __forceinline__ unsigned short f2bf(float f) {
  __hip_bfloat16 h = __float2bfloat16(f);   // RNE
  return *reinterpret_cast<unsigned short*>(&h);
}
__device__ __forceinline__ unsigned pkbf2(float lo, float hi) {
  __hip_bfloat162 h2 = __float22bfloat162_rn(make_float2(lo, hi)); // v_cvt_pk_bf16_f32
  return *reinterpret_cast<unsigned*>(&h2);
}

// ---------------- pass 1: repack + bias prep (merged grid) ----------------
__global__ __launch_bounds__(256, 4) void prep_kernel(
    const float* __restrict__ qkv, const float* __restrict__ table) {
  __shared__ unsigned short S[8 * 1154];
  const int bid = blockIdx.x;
  const int tid = threadIdx.x;

  if (bid >= 4096) {
    // ---- bias part: g_biasC[flat*8 + e] = bias(n, m(e)) * log2e, fp32 ----
    int flat = (bid - 4096) * 256 + tid;    // 0..393215 = (nh, qt, c, lane)
    int l  = flat & 63;
    int c  = (flat >> 6) & 15;
    int qt = (flat >> 10) & 31;
    int nh = flat >> 15;
    int ln = l & 15, g = l >> 4;
    int n = qt * 16 + ln;
    int dn = n >> 6, hn = (n >> 3) & 7, wn = n & 7;
    float e[8];
#pragma unroll
    for (int r = 0; r < 8; ++r) {
      int m = 32 * c + (r >> 2) * 16 + g * 4 + (r & 3);
      int dm = m >> 6, hm = (m >> 3) & 7, wm = m & 7;
      int idx = (dn - dm + 7) * 225 + (hn - hm + 7) * 15 + (wn - wm + 7);
      e[r] = table[idx * 12 + nh] * LOG2E;
    }
    *(float4*)&g_biasC[flat * 8]     = make_float4(e[0], e[1], e[2], e[3]);
    *(float4*)&g_biasC[flat * 8 + 4] = make_float4(e[4], e[5], e[6], e[7]);
    return;
  }

  // ---- repack part ----
  const int mh = bid & 7;
  const int md = (bid >> 3) & 7;
  const int w = bid >> 6;
  const int dblk = w >> 4, hblk = (w >> 2) & 3, wblk = w & 3;
  const int dd = (dblk * 8 + 4 + md) & 31;
  const int hh = (hblk * 8 + 4 + mh) & 31;
  const int w0 = wblk * 8 + 4;

#pragma unroll
  for (int rep = 0; rep < 9; ++rep) {
    int t = rep * 256 + tid;
    unsigned v = (unsigned)t / 288u;
    int c4 = t - (int)v * 288;
    int ww = (w0 + (int)v) & 31;
    float4 f = *(const float4*)(qkv + (((dd * 32 + hh) * 32 + ww) * 1152) + c4 * 4);
    if (c4 < 96) {      // Q channels (0..383): pre-scale by scale*log2e
      f.x *= SCL2E; f.y *= SCL2E; f.z *= SCL2E; f.w *= SCL2E;
    }
    *(uint2*)&S[v * 1154 + c4 * 4] = make_uint2(pkbf2(f.x, f.y), pkbf2(f.z, f.w));
  }
  __syncthreads();

  const int mbase = md * 64 + mh * 8;
  unsigned short* gp = (unsigned short*)g_pack4;
#pragma unroll
  for (int rep = 0; rep < 5; ++rep) {
    int t = rep * 256 + tid;                 // 1152 tasks
    if (t < 1152) {
      int chunk = t & 3;
      int mw = (t >> 2) & 7;
      int r = t >> 5;                        // 0..35
      int nh = r % 12;
      int part = r / 12;
      int ebase = mw * 1154 + part * 384 + chunk * 96 + nh;
      unsigned pk[4];
#pragma unroll
      for (int jj = 0; jj < 4; ++jj) {
        unsigned lo = S[ebase + (2 * jj) * 12];
        unsigned hi = S[ebase + (2 * jj + 1) * 12];
        pk[jj] = lo | (hi << 16);
      }
      size_t dst = ((((size_t)(part * 12 + nh) * 64 + w) * 512 + mbase + mw) * 32 + chunk * 8);
      *(uint4*)&gp[dst] = make_uint4(pk[0], pk[1], pk[2], pk[3]);
    }
  }
}

// -------- pass 2: attention (512 threads, 8 waves x 4 q-tiles, fused) --------
__global__ __launch_bounds__(512, 4) void swin_attn_kernel() {
  __shared__ __align__(16) unsigned short Klds[512 * 32];   // 32 KB, XOR-swz
  __shared__ __align__(16) unsigned short Vt[32 * 516];     // 33 KB

  const int bid = blockIdx.x;
  // Head-clustered XCD map: XCD x owns head x (64 windows) + half of head 8+x/2
  const int xcd = bid & 7;
  const int jb = bid >> 3;                   // 0..95
  int nh, w;
  if (jb < 64) { nh = xcd; w = jb; }
  else         { nh = 8 + (xcd >> 1); w = (xcd & 1) * 32 + (jb - 64); }
  const int dblk = w >> 4, hblk = (w >> 2) & 3, wblk = w & 3;
  const int bm = ((dblk == 3) ? 256 : 0) | ((hblk == 3) ? 32 : 0) |
                 ((wblk == 3) ? 4 : 0);

  const int tid = threadIdx.x;

  const unsigned short* gp = (const unsigned short*)g_pack4;
  const size_t base = ((size_t)nh * 64 + w) * (512 * 32);
  const unsigned short* Qg = gp + base;                           // part 0
  const unsigned short* Kg = gp + (size_t)1 * 12 * 64 * 512 * 32 + base;
  const unsigned short* Vg = gp + (size_t)2 * 12 * 64 * 512 * 32 + base;

  // ---- stage K: coalesced uint4 loads, swizzled b128 LDS writes ----
#pragma unroll
  for (int itr = 0; itr < 4; ++itr) {
    int flat = itr * 512 + tid;              // 0..2047
    int m = flat >> 2, chunk = flat & 3;
    uint4 d = *(const uint4*)(Kg + flat * 8);
    char* dst = (char*)Klds + m * 64 + ((chunk * 16) ^ ((m & 3) << 4));
    *(uint4*)dst = d;
  }
  // ---- stage V: coalesced uint4 loads, transpose to Vt[hd][m] ----
#pragma unroll
  for (int itr = 0; itr < 4; ++itr) {
    int flat = itr * 512 + tid;
    int m = flat >> 2, hc = flat & 3;
    uint4 d = *(const uint4*)(Vg + flat * 8);
    const unsigned u[4] = {d.x, d.y, d.z, d.w};
#pragma unroll
    for (int jj = 0; jj < 8; ++jj) {
      Vt[(hc * 8 + jj) * 516 + m] =
          (unsigned short)((u[jj >> 1] >> (16 * (jj & 1))) & 0xffffu);
    }
  }
  __syncthreads();

  const int l = tid & 63;
  const int wv = tid >> 6;                   // 0..7, owns q-tiles wv*4..wv*4+3
  const int ln = l & 15;
  const int g = l >> 4;

  union frag { unsigned u[4]; short8_t v; };

  // Q fragments for the wave's 4 q-tiles (Q already pre-scaled)
  frag qf[4];
#pragma unroll
  for (int it = 0; it < 4; ++it) {
    const int n = (wv * 4 + it) * 16 + ln;
    const uint4 qd = *(const uint4*)(Qg + n * 32 + g * 8);
    qf[it].u[0] = qd.x; qf[it].u[1] = qd.y; qf[it].u[2] = qd.z; qf[it].u[3] = qd.w;
  }
  f32x4 o0[4], o1[4], sumac[4];
#pragma unroll
  for (int it = 0; it < 4; ++it) {
    o0[it] = (f32x4)(0.0f); o1[it] = (f32x4)(0.0f); sumac[it] = (f32x4)(0.0f);
  }
  frag ones;
  ones.u[0] = 0x3F803F80u; ones.u[1] = 0x3F803F80u;
  ones.u[2] = 0x3F803F80u; ones.u[3] = 0x3F803F80u;

  // bias fragment stream (fp32, D-fragment order)
  const f32x4* bp = (const f32x4*)g_biasC +
      ((size_t)(nh * 32 + wv * 4) * 16) * 128 + l * 2;

  int nA[4];
#pragma unroll
  for (int it = 0; it < 4; ++it) nA[it] = ((wv * 4 + it) * 16 + ln) & bm;

#define CLOOP(MASKED)                                                          \
  _Pragma("unroll 1")                                                          \
  for (int c = 0; c < 16; ++c) {                                               \
    frag k0, k1, a0, a1;                                                       \
    k0.v = *(const short8_t*)((const char*)Klds +                              \
        (((2 * c) * 16 + ln) * 64 + ((g * 16) ^ ((ln & 3) << 4))));            \
    k1.v = *(const short8_t*)((const char*)Klds +                              \
        (((2 * c + 1) * 16 + ln) * 64 + ((g * 16) ^ ((ln & 3) << 4))));        \
    {                                                                          \
      const int col = c * 32 + g * 4;                                          \
      const unsigned* v00 = (const unsigned*)&Vt[ln * 516 + col];              \
      const unsigned* v01 = (const unsigned*)&Vt[ln * 516 + col + 16];         \
      a0.u[0] = v00[0]; a0.u[1] = v00[1]; a0.u[2] = v01[0]; a0.u[3] = v01[1];  \
      const unsigned* v10 = (const unsigned*)&Vt[(16 + ln) * 516 + col];       \
      const unsigned* v11 = (const unsigned*)&Vt[(16 + ln) * 516 + col + 16];  \
      a1.u[0] = v10[0]; a1.u[1] = v10[1]; a1.u[2] = v11[0]; a1.u[3] = v11[1];  \
    }                                                                          \
    const int mAnd = ((c << 5) | ((g & 1) << 2)) & bm;                         \
    _Pragma("unroll")                                                          \
    for (int it = 0; it < 4; ++it) {                                           \
      const f32x4 bc0 = bp[(it * 16 + c) * 128];                               \
      const f32x4 bc1 = bp[(it * 16 + c) * 128 + 1];                           \
      f32x4 acc0 = __builtin_amdgcn_mfma_f32_16x16x32_bf16(                    \
          k0.v, qf[it].v, bc0, 0, 0, 0);                                       \
      f32x4 acc1 = __builtin_amdgcn_mfma_f32_16x16x32_bf16(                    \
          k1.v, qf[it].v, bc1, 0, 0, 0);                                       \
      float p0 = __builtin_amdgcn_exp2f(acc0[0]);                              \
      float p1 = __builtin_amdgcn_exp2f(acc0[1]);                              \
      float p2 = __builtin_amdgcn_exp2f(acc0[2]);                              \
      float p3 = __builtin_amdgcn_exp2f(acc0[3]);                              \
      float p4 = __builtin_amdgcn_exp2f(acc1[0]);                              \
      float p5 = __builtin_amdgcn_exp2f(acc1[1]);                              \
      float p6 = __builtin_amdgcn_exp2f(acc1[2]);                              \
      float p7 = __builtin_amdgcn_exp2f(acc1[3]);                              \
      frag pf;                                                                 \
      pf.u[0] = pkbf2(p0, p1);  pf.u[1] = pkbf2(p2, p3);                       \
      pf.u[2] = pkbf2(p4, p5);  pf.u[3] = pkbf2(p6, p7);                       \
      if (MASKED) {                                                            \
        const bool keep = (nA[it] == mAnd);                                    \
        pf.u[0] = keep ? pf.u[0] : 0u;                                         \
        pf.u[1] = keep ? pf.u[1] : 0u;                                         \
        pf.u[2] = keep ? pf.u[2] : 0u;                                         \
        pf.u[3] = keep ? pf.u[3] : 0u;                                         \
      }                                                                        \
      sumac[it] = __builtin_amdgcn_mfma_f32_16x16x32_bf16(                     \
          ones.v, pf.v, sumac[it], 0, 0, 0);                                   \
      o0[it] = __builtin_amdgcn_mfma_f32_16x16x32_bf16(a0.v, pf.v, o0[it], 0, 0, 0); \
      o1[it] = __builtin_amdgcn_mfma_f32_16x16x32_bf16(a1.v, pf.v, o1[it], 0, 0, 0); \
    }                                                                          \
  }

  if (bm == 0) { CLOOP(false) } else { CLOOP(true) }
#undef CLOOP

  // ---- epilogue: every lane's sumac[it][0] is its own full row-sum ----
#pragma unroll
  for (int it = 0; it < 4; ++it) {
    const float rinv = 1.0f / sumac[it][0];
    const int qt = wv * 4 + it;
    unsigned short* gop = g_opack + ((size_t)nh * 64 + w) * 16384 + qt * 512 + ln;
#pragma unroll
    for (int r = 0; r < 4; ++r) {
      gop[(g * 4 + r) * 16] = f2bf(o0[it][r] * rinv);
      gop[(g * 4 + r + 16) * 16] = f2bf(o1[it][r] * rinv);
    }
  }
}

// ---------------- pass 3: unpack g_opack (bf16) -> out (fp32) ----------------
__global__ __launch_bounds__(256) void unpack_kernel(float* __restrict__ out) {
  __shared__ float S[32 * 388];             // 48.5 KB
  const int bid = blockIdx.x;               // 64*16 = 1024
  const int mc = bid & 15;
  const int w = bid >> 4;
  const int dblk = w >> 4, hblk = (w >> 2) & 3, wblk = w & 3;
  const int d0 = dblk * 8 + 4, h0 = hblk * 8 + 4, w0 = wblk * 8 + 4;
  const int tid = threadIdx.x;

  // load: gop[nh][w][qt][hd][tk16] (bf16) -> S[ml][hd*12+nh] (f32)
#pragma unroll
  for (int rep = 0; rep < 6; ++rep) {
    int task = rep * 256 + tid;             // 0..1535
    int tk8 = task & 1;
    int q2 = (task >> 1) & 1;
    int hd = (task >> 2) & 31;
    int nh = task >> 7;                     // 0..11
    const uint4 d = *(const uint4*)(g_opack +
        ((size_t)nh * 64 + w) * 16384 + (size_t)(mc * 2 + q2) * 512 + hd * 16 + tk8 * 8);
    const unsigned u[4] = {d.x, d.y, d.z, d.w};
#pragma unroll
    for (int jj = 0; jj < 8; ++jj) {
      unsigned bits = (u[jj >> 1] << (16 * (1 - (jj & 1)))) & 0xffff0000u;
      S[(q2 * 16 + tk8 * 8 + jj) * 388 + hd * 12 + nh] = __uint_as_float(bits);
    }
  }
  __syncthreads();

  // store: token-major, fully coalesced full-line writes
#pragma unroll
  for (int rep = 0; rep < 12; ++rep) {
    int task = rep * 256 + tid;             // 0..3071
    unsigned c4 = (unsigned)task % 96u;
    int ml = (int)((unsigned)task / 96u);
    int n = mc * 32 + ml;
    int dd = (d0 + (n >> 6)) & 31;
    int hh = (h0 + ((n >> 3) & 7)) & 31;
    int ww = (w0 + (n & 7)) & 31;
    const float4* src = (const float4*)&S[ml * 388 + c4 * 4];
    *(float4*)(out + ((size_t)((dd * 32 + hh) * 32 + ww)) * 384 + c4 * 4) = *src;
  }
}

extern "C" void kernel_launch(void* const* d_in, const int* in_sizes, int n_in,
                              void* d_out, int out_size, void* d_ws, size_t ws_size,
                              hipStream_t stream) {
  (void)in_sizes; (void)n_in; (void)out_size; (void)d_ws; (void)ws_size;
  const float* qkv = (const float*)d_in[0];          // [1,32,32,32,1152] fp32
  const float* bias_table = (const float*)d_in[1];   // [3375,12] fp32
  float* out = (float*)d_out;                        // [1,32,32,32,384] fp32

  prep_kernel<<<5632, 256, 0, stream>>>(qkv, bias_table);
  swin_attn_kernel<<<768, 512, 0, stream>>>();
  unpack_kernel<<<1024, 256, 0, stream>>>(out);
}